// Round 1
// baseline (234.711 us; speedup 1.0000x reference)
//
#include <hip/hip_runtime.h>

typedef __bf16 bf16x8 __attribute__((ext_vector_type(8)));
typedef float  f32x4  __attribute__((ext_vector_type(4)));

#define T_SEQ 2048
#define NH    16
#define HD    64
#define EMB   1024
#define BATCH 2

__device__ __forceinline__ void gload_lds16(const void* g, void* lds) {
  __builtin_amdgcn_global_load_lds(
      (__attribute__((address_space(1))) void*)(g),
      (__attribute__((address_space(3))) void*)(lds), 16, 0, 0);
}

// ---- fp32 -> bf16 straight convert (8 elems/thread) ----
__global__ __launch_bounds__(256) void cvt_bf16(const float* __restrict__ in,
                                                __bf16* __restrict__ out, int n) {
  int i = (blockIdx.x * 256 + threadIdx.x) * 8;
  if (i >= n) return;
  f32x4 a = *(const f32x4*)(in + i);
  f32x4 b = *(const f32x4*)(in + i + 4);
  bf16x8 v;
  v[0] = (__bf16)a[0]; v[1] = (__bf16)a[1]; v[2] = (__bf16)a[2]; v[3] = (__bf16)a[3];
  v[4] = (__bf16)b[0]; v[5] = (__bf16)b[1]; v[6] = (__bf16)b[2]; v[7] = (__bf16)b[3];
  *(bf16x8*)(out + i) = v;
}

// ---- fp32 [rows][cols] -> bf16 [cols][rows] (transpose + convert) ----
__global__ __launch_bounds__(256) void transpose_cvt(const float* __restrict__ in,
                                                     __bf16* __restrict__ out,
                                                     int rows, int cols) {
  __shared__ float tile[32][33];
  int c0 = blockIdx.x * 32, r0 = blockIdx.y * 32;
  int tx = threadIdx.x & 31, ty = threadIdx.x >> 5;  // ty: 0..7
#pragma unroll
  for (int j = 0; j < 32; j += 8)
    tile[ty + j][tx] = in[(size_t)(r0 + ty + j) * cols + c0 + tx];
  __syncthreads();
#pragma unroll
  for (int j = 0; j < 32; j += 8)
    out[(size_t)(c0 + ty + j) * rows + r0 + tx] = (__bf16)tile[tx][ty + j];
}

// ---- gemm_bt: C[M,N] = A[M,K] * Bt[N,K]^T, 128x128 tile, BK=32, 4 waves ----
// MODE 0: QKV epilogue -> scatter Q(*0.125)/K as [BH][T][D], V transposed [BH][D][T] (bf16)
// MODE 1: proj epilogue -> Cout = acc + bias (fp32)
template <int MODE>
__global__ __launch_bounds__(256) void gemm_bt(
    const __bf16* __restrict__ A, const __bf16* __restrict__ Bt, int K,
    __bf16* __restrict__ Qo, __bf16* __restrict__ Ko, __bf16* __restrict__ Vt,
    const float* __restrict__ bias, float* __restrict__ Cout) {
  __shared__ alignas(16) __bf16 sA[128 * 32];
  __shared__ alignas(16) __bf16 sB[128 * 32];
  const int tid = threadIdx.x;
  const int w = tid >> 6, l = tid & 63;
  const int m0 = blockIdx.y * 128, n0 = blockIdx.x * 128;
  const int lc = l & 15, lu = l >> 4;
  const int mw = (w >> 1) * 64, nw = (w & 1) * 64;
  const int rA = l >> 2;            // row within 16-row staging group
  const int kb = (l & 3) * 8;       // k halves within BK=32

  f32x4 acc[4][4] = {};

  for (int kt = 0; kt < K; kt += 32) {
#pragma unroll
    for (int i = 0; i < 2; ++i) {
      int rr = (w * 2 + i) * 16;
      gload_lds16(A  + (size_t)(m0 + rr + rA) * K + kt + kb, sA + rr * 32);
      gload_lds16(Bt + (size_t)(n0 + rr + rA) * K + kt + kb, sB + rr * 32);
    }
    asm volatile("s_waitcnt vmcnt(0)" ::: "memory");
    __syncthreads();

    bf16x8 af[4], bfr[4];
#pragma unroll
    for (int f = 0; f < 4; ++f) {
      af[f]  = *(const bf16x8*)(sA + (mw + f * 16 + lc) * 32 + lu * 8);
      bfr[f] = *(const bf16x8*)(sB + (nw + f * 16 + lc) * 32 + lu * 8);
    }
#pragma unroll
    for (int mf = 0; mf < 4; ++mf)
#pragma unroll
      for (int nf = 0; nf < 4; ++nf)
        acc[mf][nf] = __builtin_amdgcn_mfma_f32_16x16x32_bf16(af[mf], bfr[nf],
                                                              acc[mf][nf], 0, 0, 0);
    __syncthreads();
  }

  // epilogue; C/D layout: row=(l>>4)*4+r, col=l&15
#pragma unroll
  for (int mf = 0; mf < 4; ++mf) {
#pragma unroll
    for (int nf = 0; nf < 4; ++nf) {
#pragma unroll
      for (int r = 0; r < 4; ++r) {
        int mg = m0 + mw + mf * 16 + lu * 4 + r;
        int ng = n0 + nw + nf * 16 + lc;
        float v = acc[mf][nf][r];
        if (MODE == 0) {
          int part = ng >> 10;
          int h = (ng >> 6) & 15;
          int d = ng & 63;
          int b = mg >> 11;
          int t = mg & 2047;
          if (part == 0) {
            Qo[(((size_t)(b * NH + h)) * T_SEQ + t) * HD + d] = (__bf16)(v * 0.125f);
          } else if (part == 1) {
            Ko[(((size_t)(b * NH + h)) * T_SEQ + t) * HD + d] = (__bf16)v;
          } else {
            Vt[(((size_t)(b * NH + h)) * HD + d) * T_SEQ + t] = (__bf16)v;
          }
        } else {
          Cout[(size_t)mg * EMB + ng] = v + bias[ng];
        }
      }
    }
  }
}

// ---- causal flash attention: 64 q-rows/block, 4 waves x 16 rows, KBLK=64 ----
__global__ __launch_bounds__(256) void attn(
    const __bf16* __restrict__ Q,   // [BH][T][D]  (pre-scaled by 1/sqrt(D))
    const __bf16* __restrict__ K,   // [BH][T][D]
    const __bf16* __restrict__ Vt,  // [BH][D][T]
    __bf16* __restrict__ O) {       // [B*T][EMB]
  __shared__ alignas(16) __bf16 sK[64 * 64];       // [k][d]
  __shared__ alignas(16) __bf16 sV[64 * 64];       // [d][k]  (rows of Vt)
  __shared__ alignas(16) __bf16 sP[4][16 * 72];    // per-wave P, padded stride

  const int qt = blockIdx.x, bh = blockIdx.y;
  const int tid = threadIdx.x, w = tid >> 6, l = tid & 63;
  const int lc = l & 15, lu = l >> 4;

  const __bf16* Qh = Q + (size_t)bh * T_SEQ * HD;
  const __bf16* Kh = K + (size_t)bh * T_SEQ * HD;
  const __bf16* Vh = Vt + (size_t)bh * HD * T_SEQ;

  const int q0 = qt * 64 + w * 16;
  bf16x8 qf[2];
  {
    const __bf16* qrow = Qh + (size_t)(q0 + lc) * HD + lu * 8;
    qf[0] = *(const bf16x8*)(qrow);
    qf[1] = *(const bf16x8*)(qrow + 32);
  }

  f32x4 o[4] = {};
  float mrow[4], lrow[4];
#pragma unroll
  for (int r = 0; r < 4; ++r) { mrow[r] = -1e30f; lrow[r] = 0.f; }

  for (int kt = 0; kt <= qt; ++kt) {
    __syncthreads();  // prior tile's LDS reads complete before restaging
#pragma unroll
    for (int i = 0; i < 2; ++i) {
      int rr = (w * 2 + i) * 8;
      gload_lds16(Kh + (size_t)(kt * 64 + rr + (l >> 3)) * HD + (l & 7) * 8,
                  sK + rr * 64);
      gload_lds16(Vh + (size_t)(rr + (l >> 3)) * T_SEQ + kt * 64 + (l & 7) * 8,
                  sV + rr * 64);
    }
    asm volatile("s_waitcnt vmcnt(0)" ::: "memory");
    __syncthreads();

    // S = Q * K^T  (16x64 per wave)
    f32x4 s[4] = {};
#pragma unroll
    for (int ks = 0; ks < 2; ++ks)
#pragma unroll
      for (int nf = 0; nf < 4; ++nf) {
        bf16x8 kf = *(const bf16x8*)(sK + (nf * 16 + lc) * 64 + ks * 32 + lu * 8);
        s[nf] = __builtin_amdgcn_mfma_f32_16x16x32_bf16(qf[ks], kf, s[nf], 0, 0, 0);
      }

    if (kt == qt) {
#pragma unroll
      for (int nf = 0; nf < 4; ++nf)
#pragma unroll
        for (int r = 0; r < 4; ++r)
          if (nf * 16 + lc > w * 16 + lu * 4 + r) s[nf][r] = -1e30f;
    }

    // online softmax: rows are lane-local groups (same lu), cols spread over 16 lanes
#pragma unroll
    for (int r = 0; r < 4; ++r) {
      float tm = fmaxf(fmaxf(s[0][r], s[1][r]), fmaxf(s[2][r], s[3][r]));
      tm = fmaxf(tm, __shfl_xor(tm, 1));
      tm = fmaxf(tm, __shfl_xor(tm, 2));
      tm = fmaxf(tm, __shfl_xor(tm, 4));
      tm = fmaxf(tm, __shfl_xor(tm, 8));
      float mn = fmaxf(mrow[r], tm);
      float alpha = __expf(mrow[r] - mn);
      mrow[r] = mn;
      float ps = 0.f;
#pragma unroll
      for (int nf = 0; nf < 4; ++nf) {
        float p = __expf(s[nf][r] - mn);
        s[nf][r] = p;
        ps += p;
      }
      ps += __shfl_xor(ps, 1);
      ps += __shfl_xor(ps, 2);
      ps += __shfl_xor(ps, 4);
      ps += __shfl_xor(ps, 8);
      lrow[r] = lrow[r] * alpha + ps;
#pragma unroll
      for (int nf = 0; nf < 4; ++nf) o[nf][r] *= alpha;
    }

    // P (f32, C-layout) -> per-wave LDS as bf16 row-major [16][stride 72]
#pragma unroll
    for (int nf = 0; nf < 4; ++nf)
#pragma unroll
      for (int r = 0; r < 4; ++r)
        sP[w][(lu * 4 + r) * 72 + nf * 16 + lc] = (__bf16)s[nf][r];
    __syncthreads();

    // O += P * V   (A = P rows, B^T = Vt rows)
#pragma unroll
    for (int ks = 0; ks < 2; ++ks) {
      bf16x8 pa = *(const bf16x8*)(&sP[w][lc * 72 + ks * 32 + lu * 8]);
#pragma unroll
      for (int nf = 0; nf < 4; ++nf) {
        bf16x8 vb = *(const bf16x8*)(sV + (nf * 16 + lc) * 64 + ks * 32 + lu * 8);
        o[nf] = __builtin_amdgcn_mfma_f32_16x16x32_bf16(pa, vb, o[nf], 0, 0, 0);
      }
    }
  }

  // epilogue: O[b*T + q][h*64 + d] = o / lsum
  const int b = bh >> 4, h = bh & 15;
#pragma unroll
  for (int r = 0; r < 4; ++r) {
    float inv = 1.f / lrow[r];
    int qg = qt * 64 + w * 16 + lu * 4 + r;
    size_t row = (size_t)(b * T_SEQ + qg) * EMB + h * HD;
#pragma unroll
    for (int nf = 0; nf < 4; ++nf)
      O[row + nf * 16 + lc] = (__bf16)(o[nf][r] * inv);
  }
}

extern "C" void kernel_launch(void* const* d_in, const int* in_sizes, int n_in,
                              void* d_out, int out_size, void* d_ws, size_t ws_size,
                              hipStream_t stream) {
  const float* x      = (const float*)d_in[0];
  const float* w_qkv  = (const float*)d_in[1];
  const float* w_proj = (const float*)d_in[2];
  const float* b_proj = (const float*)d_in[3];
  float* out = (float*)d_out;

  // workspace layout (requires >= 40 MiB)
  char* ws = (char*)d_ws;
  __bf16* xb     = (__bf16*)(ws);                     // 8 MiB  [4096][1024]
  __bf16* wqkvT  = (__bf16*)(ws + (8u  << 20));       // 6 MiB  [3072][1024]
  __bf16* wprojT = (__bf16*)(ws + (14u << 20));       // 2 MiB  [1024][1024]
  __bf16* Qw     = (__bf16*)(ws + (16u << 20));       // 8 MiB  [32][2048][64]
  __bf16* Kw     = (__bf16*)(ws + (24u << 20));       // 8 MiB  [32][2048][64]
  __bf16* Vw     = (__bf16*)(ws + (32u << 20));       // 8 MiB  [32][64][2048]
  __bf16* Ow     = xb;                                // reuse xb after QKV GEMM

  cvt_bf16<<<2048, 256, 0, stream>>>(x, xb, 4096 * 1024);
  transpose_cvt<<<dim3(3072 / 32, 1024 / 32), 256, 0, stream>>>(w_qkv, wqkvT, 1024, 3072);
  transpose_cvt<<<dim3(1024 / 32, 1024 / 32), 256, 0, stream>>>(w_proj, wprojT, 1024, 1024);

  gemm_bt<0><<<dim3(3072 / 128, 4096 / 128), 256, 0, stream>>>(
      xb, wqkvT, 1024, Qw, Kw, Vw, nullptr, nullptr);

  attn<<<dim3(T_SEQ / 64, BATCH * NH), 256, 0, stream>>>(Qw, Kw, Vw, Ow);

  gemm_bt<1><<<dim3(1024 / 128, 4096 / 128), 256, 0, stream>>>(
      Ow, wprojT, 1024, nullptr, nullptr, nullptr, b_proj, out);
}

// Round 2
// 167.794 us; speedup vs baseline: 1.3988x; 1.3988x over previous
//
#include <hip/hip_runtime.h>

typedef __bf16 bf16x8 __attribute__((ext_vector_type(8)));
typedef float  f32x4  __attribute__((ext_vector_type(4)));

#define T_SEQ 2048
#define NH    16
#define HD    64
#define EMB   1024
#define BATCH 2
// 1/sqrt(HD) * log2(e)  — softmax done in base-2
#define QSCALE 0.18033688f

__device__ __forceinline__ void gload_lds16(const void* g, void* lds) {
  __builtin_amdgcn_global_load_lds(
      (__attribute__((address_space(1))) void*)(g),
      (__attribute__((address_space(3))) void*)(lds), 16, 0, 0);
}

// ---- fp32 -> bf16 straight convert (8 elems/thread) ----
__global__ __launch_bounds__(256) void cvt_bf16(const float* __restrict__ in,
                                                __bf16* __restrict__ out, int n) {
  int i = (blockIdx.x * 256 + threadIdx.x) * 8;
  if (i >= n) return;
  f32x4 a = *(const f32x4*)(in + i);
  f32x4 b = *(const f32x4*)(in + i + 4);
  bf16x8 v;
  v[0] = (__bf16)a[0]; v[1] = (__bf16)a[1]; v[2] = (__bf16)a[2]; v[3] = (__bf16)a[3];
  v[4] = (__bf16)b[0]; v[5] = (__bf16)b[1]; v[6] = (__bf16)b[2]; v[7] = (__bf16)b[3];
  *(bf16x8*)(out + i) = v;
}

// ---- fp32 [rows][cols] -> bf16 [cols][rows] (transpose + convert) ----
__global__ __launch_bounds__(256) void transpose_cvt(const float* __restrict__ in,
                                                     __bf16* __restrict__ out,
                                                     int rows, int cols) {
  __shared__ float tile[32][33];
  int c0 = blockIdx.x * 32, r0 = blockIdx.y * 32;
  int tx = threadIdx.x & 31, ty = threadIdx.x >> 5;
#pragma unroll
  for (int j = 0; j < 32; j += 8)
    tile[ty + j][tx] = in[(size_t)(r0 + ty + j) * cols + c0 + tx];
  __syncthreads();
#pragma unroll
  for (int j = 0; j < 32; j += 8)
    out[(size_t)(c0 + ty + j) * rows + r0 + tx] = (__bf16)tile[tx][ty + j];
}

// ---- gemm_bt: C[M,N] = A[M,K] * Bt[N,K]^T, 128x128 tile, BK=32, 4 waves ----
template <int MODE>
__global__ __launch_bounds__(256) void gemm_bt(
    const __bf16* __restrict__ A, const __bf16* __restrict__ Bt, int K,
    __bf16* __restrict__ Qo, __bf16* __restrict__ Ko, __bf16* __restrict__ Vt,
    const float* __restrict__ bias, float* __restrict__ Cout) {
  __shared__ alignas(16) __bf16 sA[128 * 32];
  __shared__ alignas(16) __bf16 sB[128 * 32];
  const int tid = threadIdx.x;
  const int w = tid >> 6, l = tid & 63;
  const int m0 = blockIdx.y * 128, n0 = blockIdx.x * 128;
  const int lc = l & 15, lu = l >> 4;
  const int mw = (w >> 1) * 64, nw = (w & 1) * 64;
  const int rA = l >> 2;
  const int kb = (l & 3) * 8;

  f32x4 acc[4][4] = {};

  for (int kt = 0; kt < K; kt += 32) {
#pragma unroll
    for (int i = 0; i < 2; ++i) {
      int rr = (w * 2 + i) * 16;
      gload_lds16(A  + (size_t)(m0 + rr + rA) * K + kt + kb, sA + rr * 32);
      gload_lds16(Bt + (size_t)(n0 + rr + rA) * K + kt + kb, sB + rr * 32);
    }
    asm volatile("s_waitcnt vmcnt(0)" ::: "memory");
    __syncthreads();

    bf16x8 af[4], bfr[4];
#pragma unroll
    for (int f = 0; f < 4; ++f) {
      af[f]  = *(const bf16x8*)(sA + (mw + f * 16 + lc) * 32 + lu * 8);
      bfr[f] = *(const bf16x8*)(sB + (nw + f * 16 + lc) * 32 + lu * 8);
    }
#pragma unroll
    for (int mf = 0; mf < 4; ++mf)
#pragma unroll
      for (int nf = 0; nf < 4; ++nf)
        acc[mf][nf] = __builtin_amdgcn_mfma_f32_16x16x32_bf16(af[mf], bfr[nf],
                                                              acc[mf][nf], 0, 0, 0);
    __syncthreads();
  }

#pragma unroll
  for (int mf = 0; mf < 4; ++mf) {
#pragma unroll
    for (int nf = 0; nf < 4; ++nf) {
#pragma unroll
      for (int r = 0; r < 4; ++r) {
        int mg = m0 + mw + mf * 16 + lu * 4 + r;
        int ng = n0 + nw + nf * 16 + lc;
        float v = acc[mf][nf][r];
        if (MODE == 0) {
          int part = ng >> 10;
          int h = (ng >> 6) & 15;
          int d = ng & 63;
          int b = mg >> 11;
          int t = mg & 2047;
          if (part == 0) {
            Qo[(((size_t)(b * NH + h)) * T_SEQ + t) * HD + d] = (__bf16)(v * QSCALE);
          } else if (part == 1) {
            Ko[(((size_t)(b * NH + h)) * T_SEQ + t) * HD + d] = (__bf16)v;
          } else {
            Vt[(((size_t)(b * NH + h)) * HD + d) * T_SEQ + t] = (__bf16)v;
          }
        } else {
          Cout[(size_t)mg * EMB + ng] = v + bias[ng];
        }
      }
    }
  }
}

// ---- one 16x64 attention tile step for one q-subtile of one wave ----
// sK/sV hold XOR-swizzled tiles: lds[row][u16] = G[row][u16 ^ (row&7)] (16B units)
__device__ __forceinline__ void attn_tile(
    const __bf16* __restrict__ sKb, const __bf16* __restrict__ sVb,
    __bf16* __restrict__ sPw,
    const bf16x8 (&qf)[2], f32x4 (&o)[4], float (&mrow)[4], float (&lrow)[4],
    int lc, int lu, int k0, int qrow0, bool maskTile) {
  const int ru = lc & 7;
  f32x4 s[4] = {};
#pragma unroll
  for (int ks = 0; ks < 2; ++ks)
#pragma unroll
    for (int nf = 0; nf < 4; ++nf) {
      bf16x8 kf = *(const bf16x8*)(sKb + (nf * 16 + lc) * 64 +
                                   (((ks * 4 + lu) ^ ru)) * 8);
      s[nf] = __builtin_amdgcn_mfma_f32_16x16x32_bf16(qf[ks], kf, s[nf], 0, 0, 0);
    }
  if (maskTile) {
#pragma unroll
    for (int nf = 0; nf < 4; ++nf)
#pragma unroll
      for (int r = 0; r < 4; ++r)
        if (k0 + nf * 16 + lc > qrow0 + r) s[nf][r] = -1e30f;
  }
#pragma unroll
  for (int r = 0; r < 4; ++r) {
    float tm = fmaxf(fmaxf(s[0][r], s[1][r]), fmaxf(s[2][r], s[3][r]));
    tm = fmaxf(tm, __shfl_xor(tm, 1));
    tm = fmaxf(tm, __shfl_xor(tm, 2));
    tm = fmaxf(tm, __shfl_xor(tm, 4));
    tm = fmaxf(tm, __shfl_xor(tm, 8));
    float mn = fmaxf(mrow[r], tm);
    float alpha = exp2f(mrow[r] - mn);
    mrow[r] = mn;
    float ps = 0.f;
#pragma unroll
    for (int nf = 0; nf < 4; ++nf) {
      float pv = exp2f(s[nf][r] - mn);
      s[nf][r] = pv;
      ps += pv;
    }
    ps += __shfl_xor(ps, 1);
    ps += __shfl_xor(ps, 2);
    ps += __shfl_xor(ps, 4);
    ps += __shfl_xor(ps, 8);
    lrow[r] = lrow[r] * alpha + ps;
#pragma unroll
    for (int nf = 0; nf < 4; ++nf) o[nf][r] *= alpha;
  }
#pragma unroll
  for (int nf = 0; nf < 4; ++nf)
#pragma unroll
    for (int r = 0; r < 4; ++r)
      sPw[(lu * 4 + r) * 72 + nf * 16 + lc] = (__bf16)s[nf][r];
  // in-wave lgkmcnt ordering covers sP write->read; no barrier needed
#pragma unroll
  for (int ks = 0; ks < 2; ++ks) {
    bf16x8 pa = *(const bf16x8*)(sPw + lc * 72 + ks * 32 + lu * 8);
#pragma unroll
    for (int nf = 0; nf < 4; ++nf) {
      bf16x8 vb = *(const bf16x8*)(sVb + (nf * 16 + lc) * 64 +
                                   (((ks * 4 + lu) ^ ru)) * 8);
      o[nf] = __builtin_amdgcn_mfma_f32_16x16x32_bf16(pa, vb, o[nf], 0, 0, 0);
    }
  }
}

// ---- causal flash attention, paired q-tiles (p, 31-p), double-buffered K/V ----
__global__ __launch_bounds__(256) void attn(
    const __bf16* __restrict__ Q,   // [BH][T][D]  (pre-scaled)
    const __bf16* __restrict__ K,   // [BH][T][D]
    const __bf16* __restrict__ Vt,  // [BH][D][T]
    __bf16* __restrict__ O) {       // [B*T][EMB]
  __shared__ alignas(16) __bf16 sK[2][64 * 64];
  __shared__ alignas(16) __bf16 sV[2][64 * 64];
  __shared__ alignas(16) __bf16 sP[8][16 * 72];

  const int p = blockIdx.x, bh = blockIdx.y;
  const int tid = threadIdx.x, w = tid >> 6, l = tid & 63;
  const int lc = l & 15, lu = l >> 4;
  const int qtl = p, qth = 31 - p, nt = qth + 1;

  const __bf16* Qh = Q + (size_t)bh * T_SEQ * HD;
  const __bf16* Kh = K + (size_t)bh * T_SEQ * HD;
  const __bf16* Vh = Vt + (size_t)bh * HD * T_SEQ;

  const int q0l = qtl * 64 + w * 16, q0h = qth * 64 + w * 16;
  bf16x8 qfl[2], qfh[2];
  {
    const __bf16* qr = Qh + (size_t)(q0l + lc) * HD + lu * 8;
    qfl[0] = *(const bf16x8*)qr; qfl[1] = *(const bf16x8*)(qr + 32);
    qr = Qh + (size_t)(q0h + lc) * HD + lu * 8;
    qfh[0] = *(const bf16x8*)qr; qfh[1] = *(const bf16x8*)(qr + 32);
  }

  f32x4 ol[4] = {}, oh[4] = {};
  float ml[4], ll[4], mh[4], lh[4];
#pragma unroll
  for (int r = 0; r < 4; ++r) { ml[r] = mh[r] = -1e30f; ll[r] = lh[r] = 0.f; }

  // staging geometry: per call, 8 rows x 8 units of 16B; inverse-swizzle source
  const int r8 = l >> 3;
  const int usw = ((l & 7) ^ r8) * 8;  // bf16 elems

  // prologue: stage tile 0 into buf 0
#pragma unroll
  for (int i = 0; i < 2; ++i) {
    int rr = (w * 2 + i) * 8;
    gload_lds16(Kh + (size_t)(rr + r8) * HD + usw, &sK[0][rr * 64]);
    gload_lds16(Vh + (size_t)(rr + r8) * T_SEQ + usw, &sV[0][rr * 64]);
  }
  asm volatile("s_waitcnt vmcnt(0)" ::: "memory");
  __syncthreads();

  int cur = 0;
  for (int t = 0; t < nt; ++t) {
    if (t + 1 < nt) {
      int k0n = (t + 1) * 64;
#pragma unroll
      for (int i = 0; i < 2; ++i) {
        int rr = (w * 2 + i) * 8;
        gload_lds16(Kh + (size_t)(k0n + rr + r8) * HD + usw, &sK[cur ^ 1][rr * 64]);
        gload_lds16(Vh + (size_t)(rr + r8) * T_SEQ + k0n + usw, &sV[cur ^ 1][rr * 64]);
      }
    }
    const int k0 = t * 64;
    attn_tile(sK[cur], sV[cur], sP[w * 2], qfh, oh, mh, lh,
              lc, lu, k0, q0h + lu * 4, t == qth);
    if (t <= qtl)
      attn_tile(sK[cur], sV[cur], sP[w * 2 + 1], qfl, ol, ml, ll,
                lc, lu, k0, q0l + lu * 4, t == qtl);
    asm volatile("s_waitcnt vmcnt(0)" ::: "memory");
    __syncthreads();
    cur ^= 1;
  }

  const int b = bh >> 4, h = bh & 15;
#pragma unroll
  for (int r = 0; r < 4; ++r) {
    float invl = 1.f / ll[r], invh = 1.f / lh[r];
    int qgl = q0l + lu * 4 + r, qgh = q0h + lu * 4 + r;
    size_t rowl = (size_t)(b * T_SEQ + qgl) * EMB + h * HD;
    size_t rowh = (size_t)(b * T_SEQ + qgh) * EMB + h * HD;
#pragma unroll
    for (int nf = 0; nf < 4; ++nf) {
      O[rowl + nf * 16 + lc] = (__bf16)(ol[nf][r] * invl);
      O[rowh + nf * 16 + lc] = (__bf16)(oh[nf][r] * invh);
    }
  }
}

extern "C" void kernel_launch(void* const* d_in, const int* in_sizes, int n_in,
                              void* d_out, int out_size, void* d_ws, size_t ws_size,
                              hipStream_t stream) {
  const float* x      = (const float*)d_in[0];
  const float* w_qkv  = (const float*)d_in[1];
  const float* w_proj = (const float*)d_in[2];
  const float* b_proj = (const float*)d_in[3];
  float* out = (float*)d_out;

  char* ws = (char*)d_ws;
  __bf16* xb     = (__bf16*)(ws);                     // 8 MiB
  __bf16* wqkvT  = (__bf16*)(ws + (8u  << 20));       // 6 MiB
  __bf16* wprojT = (__bf16*)(ws + (14u << 20));       // 2 MiB
  __bf16* Qw     = (__bf16*)(ws + (16u << 20));       // 8 MiB
  __bf16* Kw     = (__bf16*)(ws + (24u << 20));       // 8 MiB
  __bf16* Vw     = (__bf16*)(ws + (32u << 20));       // 8 MiB
  __bf16* Ow     = xb;                                // reuse after QKV GEMM

  cvt_bf16<<<2048, 256, 0, stream>>>(x, xb, 4096 * 1024);
  transpose_cvt<<<dim3(3072 / 32, 1024 / 32), 256, 0, stream>>>(w_qkv, wqkvT, 1024, 3072);
  transpose_cvt<<<dim3(1024 / 32, 1024 / 32), 256, 0, stream>>>(w_proj, wprojT, 1024, 1024);

  gemm_bt<0><<<dim3(3072 / 128, 4096 / 128), 256, 0, stream>>>(
      xb, wqkvT, 1024, Qw, Kw, Vw, nullptr, nullptr);

  attn<<<dim3(16, BATCH * NH), 256, 0, stream>>>(Qw, Kw, Vw, Ow);

  gemm_bt<1><<<dim3(1024 / 128, 4096 / 128), 256, 0, stream>>>(
      Ow, wprojT, 1024, nullptr, nullptr, nullptr, b_proj, out);
}

// Round 3
// 153.813 us; speedup vs baseline: 1.5259x; 1.0909x over previous
//
#include <hip/hip_runtime.h>

typedef __bf16 bf16x8 __attribute__((ext_vector_type(8)));
typedef __bf16 bf16x4 __attribute__((ext_vector_type(4)));
typedef float  f32x4  __attribute__((ext_vector_type(4)));
typedef float  f32x16 __attribute__((ext_vector_type(16)));
typedef unsigned u32x2 __attribute__((ext_vector_type(2)));
typedef unsigned u32x4 __attribute__((ext_vector_type(4)));

#define T_SEQ 2048
#define NH    16
#define HD    64
#define EMB   1024
#define BATCH 2
// 1/sqrt(HD) * log2(e) — softmax in base 2
#define QSCALE 0.18033688f

__device__ __forceinline__ void gload_lds16(const void* g, void* lds) {
  __builtin_amdgcn_global_load_lds(
      (__attribute__((address_space(1))) void*)(g),
      (__attribute__((address_space(3))) void*)(lds), 16, 0, 0);
}

__device__ __forceinline__ f32x16 mfma32(bf16x8 a, bf16x8 b, f32x16 c) {
  return __builtin_amdgcn_mfma_f32_32x32x16_bf16(a, b, c, 0, 0, 0);
}

__device__ __forceinline__ unsigned cvtpk(float lo, float hi) {
  unsigned short a = __builtin_bit_cast(unsigned short, (__bf16)lo);
  unsigned short b = __builtin_bit_cast(unsigned short, (__bf16)hi);
  return (unsigned)a | ((unsigned)b << 16);
}

// ---- fp32 -> bf16 straight convert ----
__global__ __launch_bounds__(256) void cvt_bf16(const float* __restrict__ in,
                                                __bf16* __restrict__ out, int n) {
  int i = (blockIdx.x * 256 + threadIdx.x) * 8;
  if (i >= n) return;
  f32x4 a = *(const f32x4*)(in + i);
  f32x4 b = *(const f32x4*)(in + i + 4);
  bf16x8 v;
  v[0] = (__bf16)a[0]; v[1] = (__bf16)a[1]; v[2] = (__bf16)a[2]; v[3] = (__bf16)a[3];
  v[4] = (__bf16)b[0]; v[5] = (__bf16)b[1]; v[6] = (__bf16)b[2]; v[7] = (__bf16)b[3];
  *(bf16x8*)(out + i) = v;
}

// ---- fp32 [rows][cols] -> bf16 [cols][rows] ----
__global__ __launch_bounds__(256) void transpose_cvt(const float* __restrict__ in,
                                                     __bf16* __restrict__ out,
                                                     int rows, int cols) {
  __shared__ float tile[32][33];
  int c0 = blockIdx.x * 32, r0 = blockIdx.y * 32;
  int tx = threadIdx.x & 31, ty = threadIdx.x >> 5;
#pragma unroll
  for (int j = 0; j < 32; j += 8)
    tile[ty + j][tx] = in[(size_t)(r0 + ty + j) * cols + c0 + tx];
  __syncthreads();
#pragma unroll
  for (int j = 0; j < 32; j += 8)
    out[(size_t)(c0 + ty + j) * rows + r0 + tx] = (__bf16)tile[tx][ty + j];
}

// ---- gemm_bt: C[M,N] = A[M,K] * Bt[N,K]^T, 128x128 tile, BK=32, 4 waves ----
template <int MODE>
__global__ __launch_bounds__(256) void gemm_bt(
    const __bf16* __restrict__ A, const __bf16* __restrict__ Bt, int K,
    __bf16* __restrict__ Qo, __bf16* __restrict__ Ko, __bf16* __restrict__ Vt,
    const float* __restrict__ bias, float* __restrict__ Cout) {
  __shared__ alignas(16) __bf16 sA[128 * 32];
  __shared__ alignas(16) __bf16 sB[128 * 32];
  const int tid = threadIdx.x;
  const int w = tid >> 6, l = tid & 63;
  const int m0 = blockIdx.y * 128, n0 = blockIdx.x * 128;
  const int lc = l & 15, lu = l >> 4;
  const int mw = (w >> 1) * 64, nw = (w & 1) * 64;
  const int rA = l >> 2;
  const int kb = (l & 3) * 8;

  f32x4 acc[4][4] = {};

  for (int kt = 0; kt < K; kt += 32) {
#pragma unroll
    for (int i = 0; i < 2; ++i) {
      int rr = (w * 2 + i) * 16;
      gload_lds16(A  + (size_t)(m0 + rr + rA) * K + kt + kb, sA + rr * 32);
      gload_lds16(Bt + (size_t)(n0 + rr + rA) * K + kt + kb, sB + rr * 32);
    }
    asm volatile("s_waitcnt vmcnt(0)" ::: "memory");
    __syncthreads();

    bf16x8 af[4], bfr[4];
#pragma unroll
    for (int f = 0; f < 4; ++f) {
      af[f]  = *(const bf16x8*)(sA + (mw + f * 16 + lc) * 32 + lu * 8);
      bfr[f] = *(const bf16x8*)(sB + (nw + f * 16 + lc) * 32 + lu * 8);
    }
#pragma unroll
    for (int mf = 0; mf < 4; ++mf)
#pragma unroll
      for (int nf = 0; nf < 4; ++nf)
        acc[mf][nf] = __builtin_amdgcn_mfma_f32_16x16x32_bf16(af[mf], bfr[nf],
                                                              acc[mf][nf], 0, 0, 0);
    __syncthreads();
  }

#pragma unroll
  for (int mf = 0; mf < 4; ++mf) {
#pragma unroll
    for (int nf = 0; nf < 4; ++nf) {
#pragma unroll
      for (int r = 0; r < 4; ++r) {
        int mg = m0 + mw + mf * 16 + lu * 4 + r;
        int ng = n0 + nw + nf * 16 + lc;
        float v = acc[mf][nf][r];
        if (MODE == 0) {
          int part = ng >> 10;
          int h = (ng >> 6) & 15;
          int d = ng & 63;
          int b = mg >> 11;
          int t = mg & 2047;
          if (part == 0) {
            Qo[(((size_t)(b * NH + h)) * T_SEQ + t) * HD + d] = (__bf16)(v * QSCALE);
          } else if (part == 1) {
            Ko[(((size_t)(b * NH + h)) * T_SEQ + t) * HD + d] = (__bf16)v;
          } else {
            Vt[(((size_t)(b * NH + h)) * HD + d) * T_SEQ + t] = (__bf16)v;
          }
        } else {
          Cout[(size_t)mg * EMB + ng] = v + bias[ng];
        }
      }
    }
  }
}

// ---- LDS fragment read with XOR swizzle on 16B units ----
__device__ __forceinline__ bf16x8 lfrag(const __bf16* b, int row, int u) {
  return *(const bf16x8*)(b + row * 64 + ((u ^ (row & 7)) << 3));
}

// ---- causal mask on S^T (rows=k, col=q per lane) ----
__device__ __forceinline__ void cmask(f32x16& s0, f32x16& s1, int k0, int hi, int q) {
#pragma unroll
  for (int r = 0; r < 16; ++r) {
    int kk = k0 + 4 * hi + (r & 3) + 8 * (r >> 2);
    if (kk > q) s0[r] = -1e30f;
    if (kk + 32 > q) s1[r] = -1e30f;
  }
}

// ---- in-register online softmax + P packing (T12/T13) ----
__device__ __forceinline__ void softmax_pack(
    f32x16& s0, f32x16& s1, f32x16& o0, f32x16& o1,
    float& m, float& ls, u32x4 (&pf)[4]) {
  float pmax = s0[0];
#pragma unroll
  for (int r = 1; r < 16; ++r) pmax = fmaxf(pmax, s0[r]);
#pragma unroll
  for (int r = 0; r < 16; ++r) pmax = fmaxf(pmax, s1[r]);
  pmax = fmaxf(pmax, __shfl_xor(pmax, 32));
  if (!__all(pmax <= m + 8.0f)) {       // defer-max: rescale only when needed
    float mn = fmaxf(m, pmax);
    float al = __builtin_amdgcn_exp2f(m - mn);
    m = mn;
    ls *= al;
#pragma unroll
    for (int r = 0; r < 16; ++r) { o0[r] *= al; o1[r] *= al; }
  }
  float ps = 0.f;
  f32x16 p0, p1;
#pragma unroll
  for (int r = 0; r < 16; ++r) {
    p0[r] = __builtin_amdgcn_exp2f(s0[r] - m); ps += p0[r];
    p1[r] = __builtin_amdgcn_exp2f(s1[r] - m); ps += p1[r];
  }
  ps += __shfl_xor(ps, 32);
  ls += ps;
  // pack P^T into B-fragments: lane needs k = ks*16 + (l>>5)*8 + j for its q
#pragma unroll
  for (int kt = 0; kt < 2; ++kt) {
    const f32x16& p = kt ? p1 : p0;
#pragma unroll
    for (int kh = 0; kh < 2; ++kh) {
      unsigned c01 = cvtpk(p[kh * 8 + 0], p[kh * 8 + 1]);
      unsigned c23 = cvtpk(p[kh * 8 + 2], p[kh * 8 + 3]);
      unsigned c45 = cvtpk(p[kh * 8 + 4], p[kh * 8 + 5]);
      unsigned c67 = cvtpk(p[kh * 8 + 6], p[kh * 8 + 7]);
      u32x2 a = __builtin_amdgcn_permlane32_swap(c01, c45, false, false);
      u32x2 c = __builtin_amdgcn_permlane32_swap(c23, c67, false, false);
      u32x4 r; r[0] = a[0]; r[1] = c[0]; r[2] = a[1]; r[3] = c[1];
      pf[kt * 2 + kh] = r;
    }
  }
}

// ---- causal flash attention: swapped QK^T, in-register softmax ----
// block = 2 waves, each wave: one 32-row subtile of low chunk x and high chunk 31-x
__global__ __launch_bounds__(128, 2) void attn(
    const __bf16* __restrict__ Q,   // [BH][T][D] pre-scaled by QSCALE
    const __bf16* __restrict__ K,   // [BH][T][D]
    const __bf16* __restrict__ Vt,  // [BH][D][T]
    __bf16* __restrict__ O) {       // [B*T][EMB]
  __shared__ alignas(16) __bf16 sK[2][64 * 64];
  __shared__ alignas(16) __bf16 sV[2][64 * 64];

  const int x = blockIdx.x, bh = blockIdx.y;
  const int tid = threadIdx.x, w = tid >> 6, l = tid & 63;
  const int lq = l & 31, hi = l >> 5;

  const __bf16* Qh = Q + (size_t)bh * T_SEQ * HD;
  const __bf16* Kh = K + (size_t)bh * T_SEQ * HD;
  const __bf16* Vh = Vt + (size_t)bh * HD * T_SEQ;

  const int qL = x * 64 + w * 32;
  const int qH = (31 - x) * 64 + w * 32;
  const int nt = 32 - x;

  bf16x8 qfL[4], qfH[4];
#pragma unroll
  for (int dc = 0; dc < 4; ++dc) {
    qfL[dc] = *(const bf16x8*)(Qh + (size_t)(qL + lq) * HD + dc * 16 + hi * 8);
    qfH[dc] = *(const bf16x8*)(Qh + (size_t)(qH + lq) * HD + dc * 16 + hi * 8);
  }

  f32x16 oL0 = {}, oL1 = {}, oH0 = {}, oH1 = {};
  float mL = -1e30f, lsL = 0.f, mH = -1e30f, lsH = 0.f;

  const int srow = tid >> 3;                       // 0..15
  const int usw = ((tid & 7) ^ (srow & 7)) * 8;    // inverse-swizzled source unit

  auto stage = [&](int buf, int k0) {
#pragma unroll
    for (int i = 0; i < 4; ++i) {
      gload_lds16(Kh + (size_t)(k0 + i * 16 + srow) * HD + usw,
                  &sK[buf][(i * 16 + w * 8) * 64]);
      gload_lds16(Vh + (size_t)(i * 16 + srow) * T_SEQ + k0 + usw,
                  &sV[buf][(i * 16 + w * 8) * 64]);
    }
  };

  stage(0, 0);
  asm volatile("s_waitcnt vmcnt(0)" ::: "memory");
  __syncthreads();

  int cur = 0;
  for (int t = 0; t < nt; ++t) {
    if (t + 1 < nt) stage(cur ^ 1, (t + 1) * 64);
    const bool doL = (t <= x);
    const __bf16* sKb = sK[cur];
    const __bf16* sVb = sV[cur];

    // S^T = K * Q^T (both subtiles share K fragments)
    f32x16 sH0 = {}, sH1 = {}, sL0 = {}, sL1 = {};
#pragma unroll
    for (int dc = 0; dc < 4; ++dc) {
      bf16x8 kf0 = lfrag(sKb, lq, dc * 2 + hi);
      bf16x8 kf1 = lfrag(sKb, 32 + lq, dc * 2 + hi);
      sH0 = mfma32(kf0, qfH[dc], sH0);
      sH1 = mfma32(kf1, qfH[dc], sH1);
      if (doL) {
        sL0 = mfma32(kf0, qfL[dc], sL0);
        sL1 = mfma32(kf1, qfL[dc], sL1);
      }
    }

    const int k0 = t * 64;
    if (t == nt - 1) cmask(sH0, sH1, k0, hi, qH + lq);
    u32x4 pfH[4], pfL[4];
    softmax_pack(sH0, sH1, oH0, oH1, mH, lsH, pfH);
    if (doL) {
      if (t == x) cmask(sL0, sL1, k0, hi, qL + lq);
      softmax_pack(sL0, sL1, oL0, oL1, mL, lsL, pfL);
    }

    // O^T += V^T * P^T (V fragments shared)
#pragma unroll
    for (int ks = 0; ks < 4; ++ks) {
      bf16x8 vf0 = lfrag(sVb, lq, ks * 2 + hi);
      bf16x8 vf1 = lfrag(sVb, 32 + lq, ks * 2 + hi);
      bf16x8 pH = __builtin_bit_cast(bf16x8, pfH[ks]);
      oH0 = mfma32(vf0, pH, oH0);
      oH1 = mfma32(vf1, pH, oH1);
      if (doL) {
        bf16x8 pL = __builtin_bit_cast(bf16x8, pfL[ks]);
        oL0 = mfma32(vf0, pL, oL0);
        oL1 = mfma32(vf1, pL, oL1);
      }
    }

    asm volatile("s_waitcnt vmcnt(0)" ::: "memory");
    __syncthreads();
    cur ^= 1;
  }

  // epilogue: O^T col=q is lane-local; rows d = (r&3)+8*(r>>2)+4*hi (+32*dt)
  const int b = bh >> 4, h = bh & 15;
  const float invH = 1.f / lsH, invL = 1.f / lsL;
  size_t rowH = (size_t)(b * T_SEQ + qH + lq) * EMB + h * HD;
  size_t rowL = (size_t)(b * T_SEQ + qL + lq) * EMB + h * HD;
#pragma unroll
  for (int dt = 0; dt < 2; ++dt) {
    const f32x16& ovH = dt ? oH1 : oH0;
    const f32x16& ovL = dt ? oL1 : oL0;
#pragma unroll
    for (int rg = 0; rg < 4; ++rg) {
      bf16x4 vH, vL;
#pragma unroll
      for (int j = 0; j < 4; ++j) {
        vH[j] = (__bf16)(ovH[rg * 4 + j] * invH);
        vL[j] = (__bf16)(ovL[rg * 4 + j] * invL);
      }
      int d = dt * 32 + rg * 8 + 4 * hi;
      *(bf16x4*)(O + rowH + d) = vH;
      *(bf16x4*)(O + rowL + d) = vL;
    }
  }
}

extern "C" void kernel_launch(void* const* d_in, const int* in_sizes, int n_in,
                              void* d_out, int out_size, void* d_ws, size_t ws_size,
                              hipStream_t stream) {
  const float* x      = (const float*)d_in[0];
  const float* w_qkv  = (const float*)d_in[1];
  const float* w_proj = (const float*)d_in[2];
  const float* b_proj = (const float*)d_in[3];
  float* out = (float*)d_out;

  char* ws = (char*)d_ws;
  __bf16* xb     = (__bf16*)(ws);                     // 8 MiB
  __bf16* wqkvT  = (__bf16*)(ws + (8u  << 20));       // 6 MiB
  __bf16* wprojT = (__bf16*)(ws + (14u << 20));       // 2 MiB
  __bf16* Qw     = (__bf16*)(ws + (16u << 20));       // 8 MiB
  __bf16* Kw     = (__bf16*)(ws + (24u << 20));       // 8 MiB
  __bf16* Vw     = (__bf16*)(ws + (32u << 20));       // 8 MiB
  __bf16* Ow     = xb;                                // reuse after QKV GEMM

  cvt_bf16<<<2048, 256, 0, stream>>>(x, xb, 4096 * 1024);
  transpose_cvt<<<dim3(3072 / 32, 1024 / 32), 256, 0, stream>>>(w_qkv, wqkvT, 1024, 3072);
  transpose_cvt<<<dim3(1024 / 32, 1024 / 32), 256, 0, stream>>>(w_proj, wprojT, 1024, 1024);

  gemm_bt<0><<<dim3(3072 / 128, 4096 / 128), 256, 0, stream>>>(
      xb, wqkvT, 1024, Qw, Kw, Vw, nullptr, nullptr);

  attn<<<dim3(16, BATCH * NH), 128, 0, stream>>>(Qw, Kw, Vw, Ow);

  gemm_bt<1><<<dim3(1024 / 128, 4096 / 128), 256, 0, stream>>>(
      Ow, wprojT, 1024, nullptr, nullptr, nullptr, b_proj, out);
}

// Round 4
// 132.450 us; speedup vs baseline: 1.7721x; 1.1613x over previous
//
#include <hip/hip_runtime.h>

typedef __bf16 bf16x8 __attribute__((ext_vector_type(8)));
typedef __bf16 bf16x4 __attribute__((ext_vector_type(4)));
typedef float  f32x4  __attribute__((ext_vector_type(4)));
typedef float  f32x16 __attribute__((ext_vector_type(16)));
typedef unsigned u32x2 __attribute__((ext_vector_type(2)));
typedef unsigned u32x4 __attribute__((ext_vector_type(4)));

#define T_SEQ 2048
#define NH    16
#define HD    64
#define EMB   1024
#define BATCH 2
// 1/sqrt(HD) * log2(e) — softmax in base 2
#define QSCALE 0.18033688f

__device__ __forceinline__ void gload_lds16(const void* g, void* lds) {
  __builtin_amdgcn_global_load_lds(
      (__attribute__((address_space(1))) void*)(g),
      (__attribute__((address_space(3))) void*)(lds), 16, 0, 0);
}

__device__ __forceinline__ f32x16 mfma32(bf16x8 a, bf16x8 b, f32x16 c) {
  return __builtin_amdgcn_mfma_f32_32x32x16_bf16(a, b, c, 0, 0, 0);
}

__device__ __forceinline__ unsigned cvtpk(float lo, float hi) {
  unsigned short a = __builtin_bit_cast(unsigned short, (__bf16)lo);
  unsigned short b = __builtin_bit_cast(unsigned short, (__bf16)hi);
  return (unsigned)a | ((unsigned)b << 16);
}

// ---- fp32 -> bf16 straight convert ----
__global__ __launch_bounds__(256) void cvt_bf16(const float* __restrict__ in,
                                                __bf16* __restrict__ out, int n) {
  int i = (blockIdx.x * 256 + threadIdx.x) * 8;
  if (i >= n) return;
  f32x4 a = *(const f32x4*)(in + i);
  f32x4 b = *(const f32x4*)(in + i + 4);
  bf16x8 v;
  v[0] = (__bf16)a[0]; v[1] = (__bf16)a[1]; v[2] = (__bf16)a[2]; v[3] = (__bf16)a[3];
  v[4] = (__bf16)b[0]; v[5] = (__bf16)b[1]; v[6] = (__bf16)b[2]; v[7] = (__bf16)b[3];
  *(bf16x8*)(out + i) = v;
}

// ---- fp32 [rows][cols] -> bf16 [cols][rows] ----
__global__ __launch_bounds__(256) void transpose_cvt(const float* __restrict__ in,
                                                     __bf16* __restrict__ out,
                                                     int rows, int cols) {
  __shared__ float tile[32][33];
  int c0 = blockIdx.x * 32, r0 = blockIdx.y * 32;
  int tx = threadIdx.x & 31, ty = threadIdx.x >> 5;
#pragma unroll
  for (int j = 0; j < 32; j += 8)
    tile[ty + j][tx] = in[(size_t)(r0 + ty + j) * cols + c0 + tx];
  __syncthreads();
#pragma unroll
  for (int j = 0; j < 32; j += 8)
    out[(size_t)(c0 + ty + j) * rows + r0 + tx] = (__bf16)tile[tx][ty + j];
}

// ---- gemm_bt: C[M,N] = A[M,K] * Bt[N,K]^T, 128x128 tile, BK=32, 4 waves ----
template <int MODE>
__global__ __launch_bounds__(256) void gemm_bt(
    const __bf16* __restrict__ A, const __bf16* __restrict__ Bt, int K,
    __bf16* __restrict__ Qo, __bf16* __restrict__ Ko, __bf16* __restrict__ Vt,
    const float* __restrict__ bias, float* __restrict__ Cout) {
  __shared__ alignas(16) __bf16 sA[128 * 32];
  __shared__ alignas(16) __bf16 sB[128 * 32];
  const int tid = threadIdx.x;
  const int w = tid >> 6, l = tid & 63;
  const int m0 = blockIdx.y * 128, n0 = blockIdx.x * 128;
  const int lc = l & 15, lu = l >> 4;
  const int mw = (w >> 1) * 64, nw = (w & 1) * 64;
  const int rA = l >> 2;
  const int kb = (l & 3) * 8;

  f32x4 acc[4][4] = {};

  for (int kt = 0; kt < K; kt += 32) {
#pragma unroll
    for (int i = 0; i < 2; ++i) {
      int rr = (w * 2 + i) * 16;
      gload_lds16(A  + (size_t)(m0 + rr + rA) * K + kt + kb, sA + rr * 32);
      gload_lds16(Bt + (size_t)(n0 + rr + rA) * K + kt + kb, sB + rr * 32);
    }
    asm volatile("s_waitcnt vmcnt(0)" ::: "memory");
    __syncthreads();

    bf16x8 af[4], bfr[4];
#pragma unroll
    for (int f = 0; f < 4; ++f) {
      af[f]  = *(const bf16x8*)(sA + (mw + f * 16 + lc) * 32 + lu * 8);
      bfr[f] = *(const bf16x8*)(sB + (nw + f * 16 + lc) * 32 + lu * 8);
    }
#pragma unroll
    for (int mf = 0; mf < 4; ++mf)
#pragma unroll
      for (int nf = 0; nf < 4; ++nf)
        acc[mf][nf] = __builtin_amdgcn_mfma_f32_16x16x32_bf16(af[mf], bfr[nf],
                                                              acc[mf][nf], 0, 0, 0);
    __syncthreads();
  }

#pragma unroll
  for (int mf = 0; mf < 4; ++mf) {
#pragma unroll
    for (int nf = 0; nf < 4; ++nf) {
#pragma unroll
      for (int r = 0; r < 4; ++r) {
        int mg = m0 + mw + mf * 16 + lu * 4 + r;
        int ng = n0 + nw + nf * 16 + lc;
        float v = acc[mf][nf][r];
        if (MODE == 0) {
          int part = ng >> 10;
          int h = (ng >> 6) & 15;
          int d = ng & 63;
          int b = mg >> 11;
          int t = mg & 2047;
          if (part == 0) {
            Qo[(((size_t)(b * NH + h)) * T_SEQ + t) * HD + d] = (__bf16)(v * QSCALE);
          } else if (part == 1) {
            Ko[(((size_t)(b * NH + h)) * T_SEQ + t) * HD + d] = (__bf16)v;
          } else {
            Vt[(((size_t)(b * NH + h)) * HD + d) * T_SEQ + t] = (__bf16)v;
          }
        } else {
          Cout[(size_t)mg * EMB + ng] = v + bias[ng];
        }
      }
    }
  }
}

// ---- LDS fragment read with XOR swizzle on 16B units ----
__device__ __forceinline__ bf16x8 lfrag(const __bf16* b, int row, int u) {
  return *(const bf16x8*)(b + row * 64 + ((u ^ (row & 7)) << 3));
}

// ---- causal mask on S^T (rows=k, col=q per lane) ----
__device__ __forceinline__ void cmask(f32x16& s0, f32x16& s1, int k0, int hi, int q) {
#pragma unroll
  for (int r = 0; r < 16; ++r) {
    int kk = k0 + 4 * hi + (r & 3) + 8 * (r >> 2);
    if (kk > q) s0[r] = -1e30f;
    if (kk + 32 > q) s1[r] = -1e30f;
  }
}

// ---- in-register online softmax + P packing (T12/T13) ----
__device__ __forceinline__ void softmax_pack(
    f32x16& s0, f32x16& s1, f32x16& o0, f32x16& o1,
    float& m, float& ls, u32x4 (&pf)[4]) {
  float mx[16];
#pragma unroll
  for (int r = 0; r < 16; ++r) mx[r] = fmaxf(s0[r], s1[r]);
#pragma unroll
  for (int st = 8; st > 0; st >>= 1)
#pragma unroll
    for (int r = 0; r < 16; ++r) if (r < st) mx[r] = fmaxf(mx[r], mx[r + st]);
  float pmax = fmaxf(mx[0], __shfl_xor(mx[0], 32));
  if (!__all(pmax <= m + 8.0f)) {       // defer-max rescale
    float mn = fmaxf(m, pmax);
    float al = __builtin_amdgcn_exp2f(m - mn);
    m = mn;
    ls *= al;
#pragma unroll
    for (int r = 0; r < 16; ++r) { o0[r] *= al; o1[r] *= al; }
  }
  float ps = 0.f;
  f32x16 p0, p1;
#pragma unroll
  for (int r = 0; r < 16; ++r) {
    p0[r] = __builtin_amdgcn_exp2f(s0[r] - m); ps += p0[r];
    p1[r] = __builtin_amdgcn_exp2f(s1[r] - m); ps += p1[r];
  }
  ps += __shfl_xor(ps, 32);
  ls += ps;
#pragma unroll
  for (int kt = 0; kt < 2; ++kt) {
    const f32x16& p = kt ? p1 : p0;
#pragma unroll
    for (int kh = 0; kh < 2; ++kh) {
      unsigned c01 = cvtpk(p[kh * 8 + 0], p[kh * 8 + 1]);
      unsigned c23 = cvtpk(p[kh * 8 + 2], p[kh * 8 + 3]);
      unsigned c45 = cvtpk(p[kh * 8 + 4], p[kh * 8 + 5]);
      unsigned c67 = cvtpk(p[kh * 8 + 6], p[kh * 8 + 7]);
      u32x2 a = __builtin_amdgcn_permlane32_swap(c01, c45, false, false);
      u32x2 c = __builtin_amdgcn_permlane32_swap(c23, c67, false, false);
      u32x4 r; r[0] = a[0]; r[1] = c[0]; r[2] = a[1]; r[3] = c[1];
      pf[kt * 2 + kh] = r;
    }
  }
}

__device__ __forceinline__ void dump_state(float* mo, float* mm, int reg, int l,
                                           const f32x16& o0, const f32x16& o1,
                                           float m, float ls) {
  float* po = mo + reg * 2048 + l;
#pragma unroll
  for (int r = 0; r < 16; ++r) { po[r * 64] = o0[r]; po[(16 + r) * 64] = o1[r]; }
  mm[reg * 128 + l] = m;
  mm[reg * 128 + 64 + l] = ls;
}

__device__ __forceinline__ void merge_write(const float* mo, const float* mm,
                                            int reg, int l, int hi,
                                            const f32x16& o0, const f32x16& o1,
                                            float m, float ls,
                                            __bf16* O, size_t rowbase) {
  float m1 = mm[reg * 128 + l];
  float l1 = mm[reg * 128 + 64 + l];
  float mn = fmaxf(m, m1);
  float a0 = __builtin_amdgcn_exp2f(m - mn);
  float a1 = __builtin_amdgcn_exp2f(m1 - mn);
  float inv = 1.f / (ls * a0 + l1 * a1);
  const float* po = mo + reg * 2048 + l;
#pragma unroll
  for (int dt = 0; dt < 2; ++dt) {
    const f32x16& ov = dt ? o1 : o0;
#pragma unroll
    for (int rg = 0; rg < 4; ++rg) {
      bf16x4 vv;
#pragma unroll
      for (int j = 0; j < 4; ++j) {
        int r = rg * 4 + j;
        float oth = po[(dt * 16 + r) * 64];
        vv[j] = (__bf16)((ov[r] * a0 + oth * a1) * inv);
      }
      int d = dt * 32 + rg * 8 + 4 * hi;
      *(bf16x4*)(O + rowbase + d) = vv;
    }
  }
}

// ---- causal flash attention: paired chunks (x, 31-x), k-parity split ----
// 4 waves: gc = w&1 computes k-tiles of parity gc; s = w>>1 picks 32-row subtile.
__global__ __launch_bounds__(256, 2) void attn(
    const __bf16* __restrict__ Q,   // [BH][T][D] pre-scaled by QSCALE
    const __bf16* __restrict__ K,   // [BH][T][D]
    const __bf16* __restrict__ Vt,  // [BH][D][T]
    __bf16* __restrict__ O) {       // [B*T][EMB]
  __shared__ alignas(16) __bf16 sKV[8][64 * 64];   // [0..3] K slots, [4..7] V slots
  __shared__ alignas(16) float mls[4 * 2 * 64];    // merge m/ls scratch

  const int x = blockIdx.x, bh = blockIdx.y;
  const int tid = threadIdx.x, w = tid >> 6, l = tid & 63;
  const int lq = l & 31, hi = l >> 5;
  const int gc = w & 1;   // compute parity / staged-tile parity
  const int s  = w >> 1;  // subtile / staging kind (0=K, 1=V)

  const __bf16* Qh = Q + (size_t)bh * T_SEQ * HD;
  const __bf16* Kh = K + (size_t)bh * T_SEQ * HD;
  const __bf16* Vh = Vt + (size_t)bh * HD * T_SEQ;

  const int qL = x * 64 + s * 32;
  const int qH = (31 - x) * 64 + s * 32;
  const int nt = 32 - x;
  const int nsup = (nt + 1) >> 1;

  bf16x8 qfL[4], qfH[4];
#pragma unroll
  for (int dc = 0; dc < 4; ++dc) {
    qfL[dc] = *(const bf16x8*)(Qh + (size_t)(qL + lq) * HD + dc * 16 + hi * 8);
    qfH[dc] = *(const bf16x8*)(Qh + (size_t)(qH + lq) * HD + dc * 16 + hi * 8);
  }

  f32x16 oL0 = {}, oL1 = {}, oH0 = {}, oH1 = {};
  float mL = -1e30f, lsL = 0.f, mH = -1e30f, lsH = 0.f;

  const int r8 = l >> 3;
  const int uswE = ((l & 7) ^ r8) << 3;   // swizzled source unit, bf16 elems

  // wave role: stages tile (2*ss + gc), kind s (0 -> K slot, 1 -> V slot)
  auto stage = [&](int buf, int ss) {
    int t = 2 * ss + gc;
    if (t > 31) t = 31;                   // clamp (data unused, stays in range)
    int k0s = t * 64;
    __bf16* dst = &sKV[s * 4 + buf * 2 + gc][0];
    if (s == 0) {
#pragma unroll
      for (int i = 0; i < 8; ++i)
        gload_lds16(Kh + (size_t)(k0s + i * 8 + r8) * HD + uswE, dst + i * 512);
    } else {
#pragma unroll
      for (int i = 0; i < 8; ++i)
        gload_lds16(Vh + (size_t)(i * 8 + r8) * T_SEQ + k0s + uswE, dst + i * 512);
    }
  };

  stage(0, 0);
  asm volatile("s_waitcnt vmcnt(0)" ::: "memory");
  __syncthreads();

  int buf = 0;
  for (int ss = 0; ss < nsup; ++ss) {
    if (ss + 1 < nsup) stage(buf ^ 1, ss + 1);
    const int tg = 2 * ss + gc;
    const bool doH = (tg < nt);
    const bool doL = (tg <= x);
    if (doH) {
      const __bf16* sKb = &sKV[buf * 2 + gc][0];
      const __bf16* sVb = &sKV[4 + buf * 2 + gc][0];
      f32x16 sH0 = {}, sH1 = {}, sL0 = {}, sL1 = {};
#pragma unroll
      for (int dc = 0; dc < 4; ++dc) {
        bf16x8 kf0 = lfrag(sKb, lq, dc * 2 + hi);
        bf16x8 kf1 = lfrag(sKb, 32 + lq, dc * 2 + hi);
        sH0 = mfma32(kf0, qfH[dc], sH0);
        sH1 = mfma32(kf1, qfH[dc], sH1);
        if (doL) {
          sL0 = mfma32(kf0, qfL[dc], sL0);
          sL1 = mfma32(kf1, qfL[dc], sL1);
        }
      }
      const int k0 = tg * 64;
      if (tg == nt - 1) cmask(sH0, sH1, k0, hi, qH + lq);
      u32x4 pfH[4], pfL[4];
      softmax_pack(sH0, sH1, oH0, oH1, mH, lsH, pfH);
      if (doL) {
        if (tg == x) cmask(sL0, sL1, k0, hi, qL + lq);
        softmax_pack(sL0, sL1, oL0, oL1, mL, lsL, pfL);
      }
#pragma unroll
      for (int ks = 0; ks < 4; ++ks) {
        bf16x8 vf0 = lfrag(sVb, lq, ks * 2 + hi);
        bf16x8 vf1 = lfrag(sVb, 32 + lq, ks * 2 + hi);
        bf16x8 pH = __builtin_bit_cast(bf16x8, pfH[ks]);
        oH0 = mfma32(vf0, pH, oH0);
        oH1 = mfma32(vf1, pH, oH1);
        if (doL) {
          bf16x8 pL = __builtin_bit_cast(bf16x8, pfL[ks]);
          oL0 = mfma32(vf0, pL, oL0);
          oL1 = mfma32(vf1, pL, oL1);
        }
      }
    }
    asm volatile("s_waitcnt vmcnt(0)" ::: "memory");
    __syncthreads();
    buf ^= 1;
  }

  // ---- cross-group merge (odd parity dumps, even parity merges + stores) ----
  float* mo = (float*)&sKV[0][0];   // 4 regions x 32 x 64 f32 = 32 KiB (aliases sKV)
  if (gc == 1) {
    dump_state(mo, mls, s * 2 + 0, l, oH0, oH1, mH, lsH);
    dump_state(mo, mls, s * 2 + 1, l, oL0, oL1, mL, lsL);
  }
  __syncthreads();
  if (gc == 0) {
    const int b = bh >> 4, h = bh & 15;
    size_t rowH = (size_t)(b * T_SEQ + qH + lq) * EMB + h * HD;
    size_t rowL = (size_t)(b * T_SEQ + qL + lq) * EMB + h * HD;
    merge_write(mo, mls, s * 2 + 0, l, hi, oH0, oH1, mH, lsH, O, rowH);
    merge_write(mo, mls, s * 2 + 1, l, hi, oL0, oL1, mL, lsL, O, rowL);
  }
}

extern "C" void kernel_launch(void* const* d_in, const int* in_sizes, int n_in,
                              void* d_out, int out_size, void* d_ws, size_t ws_size,
                              hipStream_t stream) {
  const float* x      = (const float*)d_in[0];
  const float* w_qkv  = (const float*)d_in[1];
  const float* w_proj = (const float*)d_in[2];
  const float* b_proj = (const float*)d_in[3];
  float* out = (float*)d_out;

  char* ws = (char*)d_ws;
  __bf16* xb     = (__bf16*)(ws);                     // 8 MiB
  __bf16* wqkvT  = (__bf16*)(ws + (8u  << 20));       // 6 MiB
  __bf16* wprojT = (__bf16*)(ws + (14u << 20));       // 2 MiB
  __bf16* Qw     = (__bf16*)(ws + (16u << 20));       // 8 MiB
  __bf16* Kw     = (__bf16*)(ws + (24u << 20));       // 8 MiB
  __bf16* Vw     = (__bf16*)(ws + (32u << 20));       // 8 MiB
  __bf16* Ow     = xb;                                // reuse after QKV GEMM

  cvt_bf16<<<2048, 256, 0, stream>>>(x, xb, 4096 * 1024);
  transpose_cvt<<<dim3(3072 / 32, 1024 / 32), 256, 0, stream>>>(w_qkv, wqkvT, 1024, 3072);
  transpose_cvt<<<dim3(1024 / 32, 1024 / 32), 256, 0, stream>>>(w_proj, wprojT, 1024, 1024);

  gemm_bt<0><<<dim3(3072 / 128, 4096 / 128), 256, 0, stream>>>(
      xb, wqkvT, 1024, Qw, Kw, Vw, nullptr, nullptr);

  attn<<<dim3(16, BATCH * NH), 256, 0, stream>>>(Qw, Kw, Vw, Ow);

  gemm_bt<1><<<dim3(1024 / 128, 4096 / 128), 256, 0, stream>>>(
      Ow, wprojT, 1024, nullptr, nullptr, nullptr, b_proj, out);
}

// Round 5
// 124.846 us; speedup vs baseline: 1.8800x; 1.0609x over previous
//
#include <hip/hip_runtime.h>

typedef __bf16 bf16x8 __attribute__((ext_vector_type(8)));
typedef __bf16 bf16x4 __attribute__((ext_vector_type(4)));
typedef float  f32x4  __attribute__((ext_vector_type(4)));
typedef float  f32x16 __attribute__((ext_vector_type(16)));
typedef unsigned u32x2 __attribute__((ext_vector_type(2)));
typedef unsigned u32x4 __attribute__((ext_vector_type(4)));

#define T_SEQ 2048
#define NH    16
#define HD    64
#define EMB   1024
#define BATCH 2
// 1/sqrt(HD) * log2(e) — softmax in base 2
#define QSCALE 0.18033688f

__device__ __forceinline__ void gload_lds16(const void* g, void* lds) {
  __builtin_amdgcn_global_load_lds(
      (__attribute__((address_space(1))) void*)(g),
      (__attribute__((address_space(3))) void*)(lds), 16, 0, 0);
}

__device__ __forceinline__ f32x16 mfma32(bf16x8 a, bf16x8 b, f32x16 c) {
  return __builtin_amdgcn_mfma_f32_32x32x16_bf16(a, b, c, 0, 0, 0);
}

__device__ __forceinline__ unsigned cvtpk(float lo, float hi) {
  unsigned short a = __builtin_bit_cast(unsigned short, (__bf16)lo);
  unsigned short b = __builtin_bit_cast(unsigned short, (__bf16)hi);
  return (unsigned)a | ((unsigned)b << 16);
}

// ---- fp32 -> bf16 straight convert ----
__global__ __launch_bounds__(256) void cvt_bf16(const float* __restrict__ in,
                                                __bf16* __restrict__ out, int n) {
  int i = (blockIdx.x * 256 + threadIdx.x) * 8;
  if (i >= n) return;
  f32x4 a = *(const f32x4*)(in + i);
  f32x4 b = *(const f32x4*)(in + i + 4);
  bf16x8 v;
  v[0] = (__bf16)a[0]; v[1] = (__bf16)a[1]; v[2] = (__bf16)a[2]; v[3] = (__bf16)a[3];
  v[4] = (__bf16)b[0]; v[5] = (__bf16)b[1]; v[6] = (__bf16)b[2]; v[7] = (__bf16)b[3];
  *(bf16x8*)(out + i) = v;
}

// ---- fp32 [rows][cols] -> bf16 [cols][rows] ----
__global__ __launch_bounds__(256) void transpose_cvt(const float* __restrict__ in,
                                                     __bf16* __restrict__ out,
                                                     int rows, int cols) {
  __shared__ float tile[32][33];
  int c0 = blockIdx.x * 32, r0 = blockIdx.y * 32;
  int tx = threadIdx.x & 31, ty = threadIdx.x >> 5;
#pragma unroll
  for (int j = 0; j < 32; j += 8)
    tile[ty + j][tx] = in[(size_t)(r0 + ty + j) * cols + c0 + tx];
  __syncthreads();
#pragma unroll
  for (int j = 0; j < 32; j += 8)
    out[(size_t)(c0 + ty + j) * rows + r0 + tx] = (__bf16)tile[tx][ty + j];
}

// ---- gemm_bt: C[M,N] = A[M,K] * Bt[N,K]^T, 128x128 tile, BK=32, 4 waves ----
// Double-buffered LDS (prefetch next K-step before computing current) +
// both-sides XOR swizzle on 16B units: LDS[row][u] = G[row][u ^ ((row>>1)&3)].
template <int MODE>
__global__ __launch_bounds__(256) void gemm_bt(
    const __bf16* __restrict__ A, const __bf16* __restrict__ Bt, int K,
    __bf16* __restrict__ Qo, __bf16* __restrict__ Ko, __bf16* __restrict__ Vt,
    const float* __restrict__ bias, float* __restrict__ Cout) {
  __shared__ alignas(16) __bf16 sA[2][128 * 32];
  __shared__ alignas(16) __bf16 sB[2][128 * 32];
  const int tid = threadIdx.x;
  const int w = tid >> 6, l = tid & 63;
  const int m0 = blockIdx.y * 128, n0 = blockIdx.x * 128;
  const int lc = l & 15, lu = l >> 4;
  const int mw = (w >> 1) * 64, nw = (w & 1) * 64;
  const int rA = l >> 2;                               // staged row within 16-group
  const int usw = (((l & 3) ^ ((rA >> 1) & 3))) * 8;   // pre-swizzled source k-offset
  const int rsw = (lu ^ ((lc >> 1) & 3)) * 8;          // swizzled read k-offset

  f32x4 acc[4][4] = {};

  auto stage = [&](int buf, int kt) {
#pragma unroll
    for (int i = 0; i < 2; ++i) {
      int rr = (w * 2 + i) * 16;
      gload_lds16(A  + (size_t)(m0 + rr + rA) * K + kt + usw, &sA[buf][rr * 32]);
      gload_lds16(Bt + (size_t)(n0 + rr + rA) * K + kt + usw, &sB[buf][rr * 32]);
    }
  };

  stage(0, 0);
  asm volatile("s_waitcnt vmcnt(0)" ::: "memory");
  __syncthreads();

  int buf = 0;
  for (int kt = 0; kt < K; kt += 32) {
    if (kt + 32 < K) stage(buf ^ 1, kt + 32);

    bf16x8 af[4], bfr[4];
#pragma unroll
    for (int f = 0; f < 4; ++f) {
      af[f]  = *(const bf16x8*)(&sA[buf][(mw + f * 16 + lc) * 32 + rsw]);
      bfr[f] = *(const bf16x8*)(&sB[buf][(nw + f * 16 + lc) * 32 + rsw]);
    }
#pragma unroll
    for (int mf = 0; mf < 4; ++mf)
#pragma unroll
      for (int nf = 0; nf < 4; ++nf)
        acc[mf][nf] = __builtin_amdgcn_mfma_f32_16x16x32_bf16(af[mf], bfr[nf],
                                                              acc[mf][nf], 0, 0, 0);
    asm volatile("s_waitcnt vmcnt(0)" ::: "memory");
    __syncthreads();
    buf ^= 1;
  }

#pragma unroll
  for (int mf = 0; mf < 4; ++mf) {
#pragma unroll
    for (int nf = 0; nf < 4; ++nf) {
#pragma unroll
      for (int r = 0; r < 4; ++r) {
        int mg = m0 + mw + mf * 16 + lu * 4 + r;
        int ng = n0 + nw + nf * 16 + lc;
        float v = acc[mf][nf][r];
        if (MODE == 0) {
          int part = ng >> 10;
          int h = (ng >> 6) & 15;
          int d = ng & 63;
          int b = mg >> 11;
          int t = mg & 2047;
          if (part == 0) {
            Qo[(((size_t)(b * NH + h)) * T_SEQ + t) * HD + d] = (__bf16)(v * QSCALE);
          } else if (part == 1) {
            Ko[(((size_t)(b * NH + h)) * T_SEQ + t) * HD + d] = (__bf16)v;
          } else {
            Vt[(((size_t)(b * NH + h)) * HD + d) * T_SEQ + t] = (__bf16)v;
          }
        } else {
          Cout[(size_t)mg * EMB + ng] = v + bias[ng];
        }
      }
    }
  }
}

// ---- LDS fragment read with XOR swizzle on 16B units ----
__device__ __forceinline__ bf16x8 lfrag(const __bf16* b, int row, int u) {
  return *(const bf16x8*)(b + row * 64 + ((u ^ (row & 7)) << 3));
}

// ---- causal mask on S^T (rows=k, col=q per lane) ----
__device__ __forceinline__ void cmask(f32x16& s0, f32x16& s1, int k0, int hi, int q) {
#pragma unroll
  for (int r = 0; r < 16; ++r) {
    int kk = k0 + 4 * hi + (r & 3) + 8 * (r >> 2);
    if (kk > q) s0[r] = -1e30f;
    if (kk + 32 > q) s1[r] = -1e30f;
  }
}

// ---- in-register online softmax + P packing (T12/T13) ----
__device__ __forceinline__ void softmax_pack(
    f32x16& s0, f32x16& s1, f32x16& o0, f32x16& o1,
    float& m, float& ls, u32x4 (&pf)[4]) {
  float mx[16];
#pragma unroll
  for (int r = 0; r < 16; ++r) mx[r] = fmaxf(s0[r], s1[r]);
#pragma unroll
  for (int st = 8; st > 0; st >>= 1)
#pragma unroll
    for (int r = 0; r < 16; ++r) if (r < st) mx[r] = fmaxf(mx[r], mx[r + st]);
  float pmax = fmaxf(mx[0], __shfl_xor(mx[0], 32));
  if (!__all(pmax <= m + 8.0f)) {       // defer-max rescale
    float mn = fmaxf(m, pmax);
    float al = __builtin_amdgcn_exp2f(m - mn);
    m = mn;
    ls *= al;
#pragma unroll
    for (int r = 0; r < 16; ++r) { o0[r] *= al; o1[r] *= al; }
  }
  float ps = 0.f;
  f32x16 p0, p1;
#pragma unroll
  for (int r = 0; r < 16; ++r) {
    p0[r] = __builtin_amdgcn_exp2f(s0[r] - m); ps += p0[r];
    p1[r] = __builtin_amdgcn_exp2f(s1[r] - m); ps += p1[r];
  }
  ps += __shfl_xor(ps, 32);
  ls += ps;
#pragma unroll
  for (int kt = 0; kt < 2; ++kt) {
    const f32x16& p = kt ? p1 : p0;
#pragma unroll
    for (int kh = 0; kh < 2; ++kh) {
      unsigned c01 = cvtpk(p[kh * 8 + 0], p[kh * 8 + 1]);
      unsigned c23 = cvtpk(p[kh * 8 + 2], p[kh * 8 + 3]);
      unsigned c45 = cvtpk(p[kh * 8 + 4], p[kh * 8 + 5]);
      unsigned c67 = cvtpk(p[kh * 8 + 6], p[kh * 8 + 7]);
      u32x2 a = __builtin_amdgcn_permlane32_swap(c01, c45, false, false);
      u32x2 c = __builtin_amdgcn_permlane32_swap(c23, c67, false, false);
      u32x4 r; r[0] = a[0]; r[1] = c[0]; r[2] = a[1]; r[3] = c[1];
      pf[kt * 2 + kh] = r;
    }
  }
}

__device__ __forceinline__ void dump_state(float* mo, float* mm, int reg, int l,
                                           const f32x16& o0, const f32x16& o1,
                                           float m, float ls) {
  float* po = mo + reg * 2048 + l;
#pragma unroll
  for (int r = 0; r < 16; ++r) { po[r * 64] = o0[r]; po[(16 + r) * 64] = o1[r]; }
  mm[reg * 128 + l] = m;
  mm[reg * 128 + 64 + l] = ls;
}

__device__ __forceinline__ void merge_write(const float* mo, const float* mm,
                                            int reg, int l, int hi,
                                            const f32x16& o0, const f32x16& o1,
                                            float m, float ls,
                                            __bf16* O, size_t rowbase) {
  float m1 = mm[reg * 128 + l];
  float l1 = mm[reg * 128 + 64 + l];
  float mn = fmaxf(m, m1);
  float a0 = __builtin_amdgcn_exp2f(m - mn);
  float a1 = __builtin_amdgcn_exp2f(m1 - mn);
  float inv = 1.f / (ls * a0 + l1 * a1);
  const float* po = mo + reg * 2048 + l;
#pragma unroll
  for (int dt = 0; dt < 2; ++dt) {
    const f32x16& ov = dt ? o1 : o0;
#pragma unroll
    for (int rg = 0; rg < 4; ++rg) {
      bf16x4 vv;
#pragma unroll
      for (int j = 0; j < 4; ++j) {
        int r = rg * 4 + j;
        float oth = po[(dt * 16 + r) * 64];
        vv[j] = (__bf16)((ov[r] * a0 + oth * a1) * inv);
      }
      int d = dt * 32 + rg * 8 + 4 * hi;
      *(bf16x4*)(O + rowbase + d) = vv;
    }
  }
}

// ---- causal flash attention: paired chunks (x, 31-x), k-parity split ----
__global__ __launch_bounds__(256, 2) void attn(
    const __bf16* __restrict__ Q,   // [BH][T][D] pre-scaled by QSCALE
    const __bf16* __restrict__ K,   // [BH][T][D]
    const __bf16* __restrict__ Vt,  // [BH][D][T]
    __bf16* __restrict__ O) {       // [B*T][EMB]
  __shared__ alignas(16) __bf16 sKV[8][64 * 64];   // [0..3] K slots, [4..7] V slots
  __shared__ alignas(16) float mls[4 * 2 * 64];    // merge m/ls scratch

  const int x = blockIdx.x, bh = blockIdx.y;
  const int tid = threadIdx.x, w = tid >> 6, l = tid & 63;
  const int lq = l & 31, hi = l >> 5;
  const int gc = w & 1;   // compute parity / staged-tile parity
  const int s  = w >> 1;  // subtile / staging kind (0=K, 1=V)

  const __bf16* Qh = Q + (size_t)bh * T_SEQ * HD;
  const __bf16* Kh = K + (size_t)bh * T_SEQ * HD;
  const __bf16* Vh = Vt + (size_t)bh * HD * T_SEQ;

  const int qL = x * 64 + s * 32;
  const int qH = (31 - x) * 64 + s * 32;
  const int nt = 32 - x;
  const int nsup = (nt + 1) >> 1;

  bf16x8 qfL[4], qfH[4];
#pragma unroll
  for (int dc = 0; dc < 4; ++dc) {
    qfL[dc] = *(const bf16x8*)(Qh + (size_t)(qL + lq) * HD + dc * 16 + hi * 8);
    qfH[dc] = *(const bf16x8*)(Qh + (size_t)(qH + lq) * HD + dc * 16 + hi * 8);
  }

  f32x16 oL0 = {}, oL1 = {}, oH0 = {}, oH1 = {};
  float mL = -1e30f, lsL = 0.f, mH = -1e30f, lsH = 0.f;

  const int r8 = l >> 3;
  const int uswE = ((l & 7) ^ r8) << 3;   // swizzled source unit, bf16 elems

  auto stage = [&](int buf, int ss) {
    int t = 2 * ss + gc;
    if (t > 31) t = 31;                   // clamp (data unused, stays in range)
    int k0s = t * 64;
    __bf16* dst = &sKV[s * 4 + buf * 2 + gc][0];
    if (s == 0) {
#pragma unroll
      for (int i = 0; i < 8; ++i)
        gload_lds16(Kh + (size_t)(k0s + i * 8 + r8) * HD + uswE, dst + i * 512);
    } else {
#pragma unroll
      for (int i = 0; i < 8; ++i)
        gload_lds16(Vh + (size_t)(i * 8 + r8) * T_SEQ + k0s + uswE, dst + i * 512);
    }
  };

  stage(0, 0);
  asm volatile("s_waitcnt vmcnt(0)" ::: "memory");
  __syncthreads();

  int buf = 0;
  for (int ss = 0; ss < nsup; ++ss) {
    if (ss + 1 < nsup) stage(buf ^ 1, ss + 1);
    const int tg = 2 * ss + gc;
    const bool doH = (tg < nt);
    const bool doL = (tg <= x);
    if (doH) {
      const __bf16* sKb = &sKV[buf * 2 + gc][0];
      const __bf16* sVb = &sKV[4 + buf * 2 + gc][0];
      f32x16 sH0 = {}, sH1 = {}, sL0 = {}, sL1 = {};
#pragma unroll
      for (int dc = 0; dc < 4; ++dc) {
        bf16x8 kf0 = lfrag(sKb, lq, dc * 2 + hi);
        bf16x8 kf1 = lfrag(sKb, 32 + lq, dc * 2 + hi);
        sH0 = mfma32(kf0, qfH[dc], sH0);
        sH1 = mfma32(kf1, qfH[dc], sH1);
        if (doL) {
          sL0 = mfma32(kf0, qfL[dc], sL0);
          sL1 = mfma32(kf1, qfL[dc], sL1);
        }
      }
      const int k0 = tg * 64;
      if (tg == nt - 1) cmask(sH0, sH1, k0, hi, qH + lq);
      u32x4 pfH[4], pfL[4];
      softmax_pack(sH0, sH1, oH0, oH1, mH, lsH, pfH);
      if (doL) {
        if (tg == x) cmask(sL0, sL1, k0, hi, qL + lq);
        softmax_pack(sL0, sL1, oL0, oL1, mL, lsL, pfL);
      }
#pragma unroll
      for (int ks = 0; ks < 4; ++ks) {
        bf16x8 vf0 = lfrag(sVb, lq, ks * 2 + hi);
        bf16x8 vf1 = lfrag(sVb, 32 + lq, ks * 2 + hi);
        bf16x8 pH = __builtin_bit_cast(bf16x8, pfH[ks]);
        oH0 = mfma32(vf0, pH, oH0);
        oH1 = mfma32(vf1, pH, oH1);
        if (doL) {
          bf16x8 pL = __builtin_bit_cast(bf16x8, pfL[ks]);
          oL0 = mfma32(vf0, pL, oL0);
          oL1 = mfma32(vf1, pL, oL1);
        }
      }
    }
    asm volatile("s_waitcnt vmcnt(0)" ::: "memory");
    __syncthreads();
    buf ^= 1;
  }

  // ---- cross-group merge (odd parity dumps, even parity merges + stores) ----
  float* mo = (float*)&sKV[0][0];   // aliases sKV after compute
  if (gc == 1) {
    dump_state(mo, mls, s * 2 + 0, l, oH0, oH1, mH, lsH);
    dump_state(mo, mls, s * 2 + 1, l, oL0, oL1, mL, lsL);
  }
  __syncthreads();
  if (gc == 0) {
    const int b = bh >> 4, h = bh & 15;
    size_t rowH = (size_t)(b * T_SEQ + qH + lq) * EMB + h * HD;
    size_t rowL = (size_t)(b * T_SEQ + qL + lq) * EMB + h * HD;
    merge_write(mo, mls, s * 2 + 0, l, hi, oH0, oH1, mH, lsH, O, rowH);
    merge_write(mo, mls, s * 2 + 1, l, hi, oL0, oL1, mL, lsL, O, rowL);
  }
}

extern "C" void kernel_launch(void* const* d_in, const int* in_sizes, int n_in,
                              void* d_out, int out_size, void* d_ws, size_t ws_size,
                              hipStream_t stream) {
  const float* x      = (const float*)d_in[0];
  const float* w_qkv  = (const float*)d_in[1];
  const float* w_proj = (const float*)d_in[2];
  const float* b_proj = (const float*)d_in[3];
  float* out = (float*)d_out;

  char* ws = (char*)d_ws;
  __bf16* xb     = (__bf16*)(ws);                     // 8 MiB
  __bf16* wqkvT  = (__bf16*)(ws + (8u  << 20));       // 6 MiB
  __bf16* wprojT = (__bf16*)(ws + (14u << 20));       // 2 MiB
  __bf16* Qw     = (__bf16*)(ws + (16u << 20));       // 8 MiB
  __bf16* Kw     = (__bf16*)(ws + (24u << 20));       // 8 MiB
  __bf16* Vw     = (__bf16*)(ws + (32u << 20));       // 8 MiB
  __bf16* Ow     = xb;                                // reuse after QKV GEMM

  cvt_bf16<<<2048, 256, 0, stream>>>(x, xb, 4096 * 1024);
  transpose_cvt<<<dim3(3072 / 32, 1024 / 32), 256, 0, stream>>>(w_qkv, wqkvT, 1024, 3072);
  transpose_cvt<<<dim3(1024 / 32, 1024 / 32), 256, 0, stream>>>(w_proj, wprojT, 1024, 1024);

  gemm_bt<0><<<dim3(3072 / 128, 4096 / 128), 256, 0, stream>>>(
      xb, wqkvT, 1024, Qw, Kw, Vw, nullptr, nullptr);

  attn<<<dim3(16, BATCH * NH), 256, 0, stream>>>(Qw, Kw, Vw, Ow);

  gemm_bt<1><<<dim3(1024 / 128, 4096 / 128), 256, 0, stream>>>(
      Ow, wprojT, 1024, nullptr, nullptr, nullptr, b_proj, out);
}